// Round 1
// 392.558 us; speedup vs baseline: 1.1344x; 1.1344x over previous
//
#include <hip/hip_runtime.h>

#define Nn 384
#define Cc 128
#define DHh 32
#define NHh 4
#define NPOS (Nn*Nn)
#define LOG2E 1.4426950408889634f

typedef unsigned short ushort_t;
typedef __attribute__((ext_vector_type(8))) short bf16x8;
typedef __attribute__((ext_vector_type(4))) float f32x4;
typedef __attribute__((ext_vector_type(16))) float f32x16;
typedef __attribute__((ext_vector_type(2))) int i32x2;
typedef __attribute__((ext_vector_type(4))) int i32x4;

__device__ __forceinline__ ushort_t f2bf(float f) {
  union { float f; unsigned int u; } v; v.f = f;
  unsigned int r = v.u + 0x7fffu + ((v.u >> 16) & 1u);   // RNE
  return (ushort_t)(r >> 16);
}
__device__ __forceinline__ float bf2f(ushort_t u) {
  union { unsigned int u; float f; } v; v.u = ((unsigned int)u) << 16;
  return v.f;
}
__device__ __forceinline__ int cvt_pk_bf16(float a, float b) {
  int r;
  asm("v_cvt_pk_bf16_f32 %0, %1, %2" : "=v"(r) : "v"(a), "v"(b));
  return r;   // lo16 = bf16(a), hi16 = bf16(b)
}

// ---------------------------------------------------------------------------
// Kernel 0: wBt[512][128] bf16 = concat(wq,wk,wv,wg); q rows scaled by
// (1/sqrt(32))*log2e (exp2 softmax trick). woT[128][128] bf16 = wo cast.
// ---------------------------------------------------------------------------
__global__ __launch_bounds__(256) void k_wt(const float* __restrict__ wq,
    const float* __restrict__ wk, const float* __restrict__ wv,
    const float* __restrict__ wg, const float* __restrict__ wo,
    ushort_t* __restrict__ wBt, ushort_t* __restrict__ woT) {
  for (int rep = 0; rep < 4; ++rep) {
    int idx = blockIdx.x * 256 + threadIdx.x + rep * 20480;  // 80 blocks
    if (idx < 65536) {
      int c = idx >> 7, k = idx & 127;
      int mat = c >> 7, row = c & 127;
      const float* src;
      float scale = 1.0f;
      if (mat == 0)      { src = wq; scale = 0.17677669529663687f * LOG2E; }
      else if (mat == 1) { src = wk; }
      else if (mat == 2) { src = wv; }
      else               { src = wg; }
      wBt[idx] = f2bf(src[row * 128 + k] * scale);
    } else {
      int j = idx - 65536;
      woT[j] = f2bf(wo[j]);
    }
  }
}

// ---------------------------------------------------------------------------
// Kernel 1: LayerNorm (wave per position) -> xn bf16; triangle bias fp32,
// TRANSPOSED layout [h][k][q] and pre-scaled by log2e.
// ---------------------------------------------------------------------------
__global__ __launch_bounds__(256) void k_ln(const float* __restrict__ x,
    const float* __restrict__ gamma, const float* __restrict__ beta,
    const float* __restrict__ wb, unsigned int* __restrict__ xnb,
    float* __restrict__ biasT) {
  int wid = threadIdx.x >> 6, lane = threadIdx.x & 63;
  int p = blockIdx.x * 4 + wid;
  int i = p / Nn, j = p - i * Nn;
  size_t base = (size_t)p * Cc + lane * 2;
  float2 xv = *(const float2*)&x[base];
  float s = xv.x + xv.y;
  #pragma unroll
  for (int off = 1; off < 64; off <<= 1) s += __shfl_xor(s, off, 64);
  float mu = s * (1.0f / Cc);
  float d0 = xv.x - mu, d1 = xv.y - mu;
  float sq = d0 * d0 + d1 * d1;
  #pragma unroll
  for (int off = 1; off < 64; off <<= 1) sq += __shfl_xor(sq, off, 64);
  float rs = rsqrtf(sq * (1.0f / Cc) + 1e-5f);
  float2 g2 = *(const float2*)&gamma[lane * 2];
  float2 b2 = *(const float2*)&beta[lane * 2];
  float xn0 = d0 * rs * g2.x + b2.x;
  float xn1 = d1 * rs * g2.y + b2.y;
  unsigned int pack = (unsigned int)f2bf(xn0) | ((unsigned int)f2bf(xn1) << 16);
  xnb[(size_t)p * 64 + lane] = pack;
  #pragma unroll
  for (int h = 0; h < NHh; ++h) {
    float2 w2 = *(const float2*)&wb[h * Cc + lane * 2];
    float t = xn0 * w2.x + xn1 * w2.y;
    #pragma unroll
    for (int off = 1; off < 64; off <<= 1) t += __shfl_xor(t, off, 64);
    if (lane == 0) biasT[(size_t)h * NPOS + j * Nn + i] = t * LOG2E;
  }
}

// ---------------------------------------------------------------------------
// Kernel 2: projection GEMM via MFMA, looping all 8 n-chunks per block so the
// A-tile is staged and frag-loaded ONCE. Cs aliases Bs. LDS 53248 -> 3 blk/CU.
// ---------------------------------------------------------------------------
__global__ __launch_bounds__(256, 3) void k_proj(const ushort_t* __restrict__ xnb,
    const ushort_t* __restrict__ wBt, const float* __restrict__ bg,
    ushort_t* __restrict__ qkvg) {
  __shared__ __align__(16) char plds[34816 + 18432];
  ushort_t* As = (ushort_t*)plds;              // [128][136]
  ushort_t* Bs = (ushort_t*)(plds + 34816);    // [64][136]  (17408 B)
  ushort_t* Cs = (ushort_t*)(plds + 34816);    // [128][72]  (18432 B, alias)
  const int tid = threadIdx.x, lane = tid & 63, w = tid >> 6;
  const int q15 = lane & 15, quad = lane >> 4;
  const int m0 = blockIdx.x * 128;

  #pragma unroll
  for (int r = 0; r < 8; ++r) {
    int idx = tid + 256 * r;
    int row = idx >> 4, seg = idx & 15;
    *(uint4*)&As[row * 136 + seg * 8] =
        *(const uint4*)&xnb[(size_t)(m0 + row) * 128 + seg * 8];
  }
  __syncthreads();
  bf16x8 af[4][2];
  #pragma unroll
  for (int kk = 0; kk < 4; ++kk)
    #pragma unroll
    for (int mi = 0; mi < 2; ++mi)
      af[kk][mi] = *(const bf16x8*)&As[(w * 32 + mi * 16 + q15) * 136 +
                                       kk * 32 + quad * 8];

  for (int nb = 0; nb < 8; ++nb) {
    #pragma unroll
    for (int r = 0; r < 4; ++r) {
      int idx = tid + 256 * r;
      int row = idx >> 4, seg = idx & 15;
      *(uint4*)&Bs[row * 136 + seg * 8] =
          *(const uint4*)&wBt[(size_t)(nb * 64 + row) * 128 + seg * 8];
    }
    __syncthreads();

    f32x4 acc[2][4];
    #pragma unroll
    for (int mi = 0; mi < 2; ++mi)
      #pragma unroll
      for (int ni = 0; ni < 4; ++ni) {
        float init = 0.0f;
        if (nb >= 6) init = bg[(nb & 1) * 64 + ni * 16 + q15];
        acc[mi][ni][0] = init; acc[mi][ni][1] = init;
        acc[mi][ni][2] = init; acc[mi][ni][3] = init;
      }
    #pragma unroll
    for (int kk = 0; kk < 4; ++kk) {
      bf16x8 bf[4];
      #pragma unroll
      for (int ni = 0; ni < 4; ++ni)
        bf[ni] = *(const bf16x8*)&Bs[(ni * 16 + q15) * 136 + kk * 32 + quad * 8];
      #pragma unroll
      for (int mi = 0; mi < 2; ++mi)
        #pragma unroll
        for (int ni = 0; ni < 4; ++ni)
          acc[mi][ni] = __builtin_amdgcn_mfma_f32_16x16x32_bf16(
              af[kk][mi], bf[ni], acc[mi][ni], 0, 0, 0);
    }
    __syncthreads();                 // Bs frag reads done (Cs aliases Bs)
    #pragma unroll
    for (int mi = 0; mi < 2; ++mi)
      #pragma unroll
      for (int ni = 0; ni < 4; ++ni)
        #pragma unroll
        for (int r = 0; r < 4; ++r) {
          int rowL = w * 32 + mi * 16 + quad * 4 + r;
          Cs[rowL * 72 + ni * 16 + q15] = f2bf(acc[mi][ni][r]);
        }
    __syncthreads();
    const int mat = nb >> 1;
    #pragma unroll
    for (int r = 0; r < 4; ++r) {
      int idx = tid + 256 * r;
      int row = idx >> 3, seg = idx & 7;
      int cl = (nb & 1) * 64 + seg * 8;
      int hh = cl >> 5, dd = cl & 31;
      uint4 v = *(const uint4*)&Cs[row * 72 + seg * 8];
      *(uint4*)&qkvg[(size_t)mat * (NHh * (size_t)NPOS * 32) +
                     (size_t)hh * ((size_t)NPOS * 32) +
                     (size_t)(m0 + row) * 32 + dd] = v;
    }
    __syncthreads();                 // Cs reads done before next Bs stage
  }
}

// ---------------------------------------------------------------------------
// Kernel 3: swapped-operand 32x32 MFMA flash attention, softmax fully in
// registers.  S^T = mfma(K,Q) so each lane owns one q-row (q = lane&31, k in
// the reg pattern).  P -> bf16 via v_cvt_pk_bf16_f32; A-fragments for PV
// assembled with 2 x v_permlane32_swap_b32 per k-slice (no P LDS round trip).
// K and V^T double-buffered in XOR-swizzled LDS; ONE barrier per chunk.
// LDS 33280 B + <=128 VGPR -> 4 blocks/CU.
// ---------------------------------------------------------------------------
__global__ __launch_bounds__(256, 4) void k_attn(const ushort_t* __restrict__ qkvg,
    const float* __restrict__ biasT, const float* __restrict__ mask,
    ushort_t* __restrict__ o_ws) {
  __shared__ __align__(16) char lds[33280];
  ushort_t* KsB = (ushort_t*)lds;              // 2 x [128][32] (8192 B each)
  ushort_t* VtB = (ushort_t*)(lds + 16384);    // 2 x [32][128] (8192 B each)
  float*  lsmem = (float*)(lds + 32768);       // [128] row sums (per-wave 32)

  const int tid = threadIdx.x, lane = tid & 63, w = tid >> 6;
  const int ql = lane & 31, h5 = lane >> 5;
  const int h  = blockIdx.x / 3;
  const int qt = blockIdx.x % 3;
  const int i  = blockIdx.y;
  const int q0 = qt * 128;

  const ushort_t* q_all = qkvg;
  const ushort_t* k_all = qkvg + (size_t)1 * NHh * NPOS * 32;
  const ushort_t* v_all = qkvg + (size_t)2 * NHh * NPOS * 32;
  const ushort_t* g_all = qkvg + (size_t)3 * NHh * NPOS * 32;
  const size_t hbase = ((size_t)h * NPOS + (size_t)i * Nn) * 32;
  const float* brow = biasT + (size_t)h * NPOS;   // [k][q], pre-scaled log2e
  const float* mrow = mask + i * Nn;

  const int qglob = q0 + w * 32 + ql;
  // Q fragments direct from global (once per block; L2-resident)
  const ushort_t* qp = q_all + hbase + (size_t)qglob * 32;
  const bf16x8 qf0 = *(const bf16x8*)&qp[h5 * 8];        // ch  0..15 half
  const bf16x8 qf1 = *(const bf16x8*)&qp[16 + h5 * 8];   // ch 16..31 half

  f32x16 oacc;
  #pragma unroll
  for (int r = 0; r < 16; ++r) oacc[r] = 0.f;
  float lsum = 0.f;

  const int swk = (ql >> 1) & 3;   // K-tile seg swizzle (read side)
  const int swv = (ql >> 1) & 7;   // V^T k-block swizzle (read side)

  for (int ch = 0; ch < 3; ++ch) {
    const int kbase = ch * 128;
    ushort_t* Ksb = KsB + (ch & 1) * 4096;
    ushort_t* Vtb = VtB + (ch & 1) * 4096;
    // ---- stage K chunk [128][32], seg ^= (row>>1)&3  (bank-conflict-free)
    #pragma unroll
    for (int r = 0; r < 2; ++r) {
      int idx = tid + 256 * r;
      int row = idx >> 2, seg = idx & 3;
      *(uint4*)&Ksb[row * 32 + (seg ^ ((row >> 1) & 3)) * 8] =
          *(const uint4*)&k_all[hbase + (size_t)(kbase + row) * 32 + seg * 8];
    }
    // ---- stage V^T [32 d][128 k] via dword-wide 2x2 transpose,
    //      k-block ^= (d>>1)&7  (2-way max on store & read)
    #pragma unroll
    for (int r = 0; r < 4; ++r) {
      int idx = tid + 256 * r;
      int dp = idx & 15, kp = idx >> 4;
      unsigned int a0 = *(const unsigned int*)
          &v_all[hbase + (size_t)(kbase + 2 * kp) * 32 + dp * 2];
      unsigned int a1 = *(const unsigned int*)
          &v_all[hbase + (size_t)(kbase + 2 * kp + 1) * 32 + dp * 2];
      unsigned int lo = (a0 & 0xffffu) | (a1 << 16);   // d=2dp   : k, k+1
      unsigned int hi = (a0 >> 16) | (a1 & 0xffff0000u); // d=2dp+1
      unsigned int* v32 = (unsigned int*)Vtb;
      int col = ((kp >> 2) ^ (dp & 7)) * 4 + (kp & 3);
      v32[(2 * dp) * 64 + col] = lo;
      v32[(2 * dp + 1) * 64 + col] = hi;
    }
    __syncthreads();   // only barrier in the chunk (dbuf covers the rest)

    #pragma unroll
    for (int t = 0; t < 4; ++t) {
      // K fragments: rows = k (lane&31), elems = channel half
      bf16x8 kf0 = *(const bf16x8*)&Ksb[(t * 32 + ql) * 32 + ((h5)     ^ swk) * 8];
      bf16x8 kf1 = *(const bf16x8*)&Ksb[(t * 32 + ql) * 32 + ((2 + h5) ^ swk) * 8];
      // C-init = tri_bias[k][q] (coalesced over q) + mask bias
      f32x16 acc;
      #pragma unroll
      for (int r = 0; r < 16; ++r) {
        int kg = kbase + t * 32 + (r & 3) + 8 * (r >> 2) + 4 * h5;
        float b = brow[kg * Nn + qglob];
        float m = mrow[kg];
        acc[r] = fmaf(m - 1.0f, 1e9f * LOG2E, b);
      }
      // S^T = K Q^T + C   (rows = k in reg pattern, cols = q = lane&31)
      acc = __builtin_amdgcn_mfma_f32_32x32x16_bf16(kf0, qf0, acc, 0, 0, 0);
      acc = __builtin_amdgcn_mfma_f32_32x32x16_bf16(kf1, qf1, acc, 0, 0, 0);
      // softmax in registers: exp2 (inputs pre-scaled), in-lane row sums,
      // packed bf16:  pk[r>>1] = {P[k], P[k+1]}
      int pk[8];
      #pragma unroll
      for (int r = 0; r < 16; r += 2) {
        float e0 = exp2f(acc[r]);
        float e1 = exp2f(acc[r + 1]);
        lsum += e0 + e1;
        pk[r >> 1] = cvt_pk_bf16(e0, e1);
      }
      // PV for k-slices kt = 2t, 2t+1: assemble pa via permlane32_swap.
      //  swap(pk[4b],pk[4b+2]) -> (pa.d0, pa.d2); (+1,+3) -> (d1, d3)
      #pragma unroll
      for (int b2 = 0; b2 < 2; ++b2) {
        i32x2 s0 = __builtin_amdgcn_permlane32_swap(pk[4 * b2 + 0],
                                                    pk[4 * b2 + 2], false, false);
        i32x2 s1 = __builtin_amdgcn_permlane32_swap(pk[4 * b2 + 1],
                                                    pk[4 * b2 + 3], false, false);
        union { i32x4 i; bf16x8 b; } pu;
        pu.i[0] = s0[0]; pu.i[1] = s1[0]; pu.i[2] = s0[1]; pu.i[3] = s1[1];
        int kt = 2 * t + b2;
        bf16x8 vb = *(const bf16x8*)
            &Vtb[ql * 128 + ((2 * kt + h5) ^ swv) * 8];
        oacc = __builtin_amdgcn_mfma_f32_32x32x16_bf16(pu.b, vb, oacc, 0, 0, 0);
      }
    }
  }

  // epilogue: complete row sums (partner half holds complementary k set),
  // broadcast per-wave via LDS, normalize, gate, store o_gated bf16.
  float lsf = lsum + __shfl_xor(lsum, 32, 64);
  if (lane < 32) lsmem[w * 32 + ql] = lsf;
  float inv[16];
  #pragma unroll
  for (int g = 0; g < 4; ++g) {
    f32x4 lv = *(const f32x4*)&lsmem[w * 32 + g * 8 + 4 * h5];
    #pragma unroll
    for (int j = 0; j < 4; ++j) inv[g * 4 + j] = 1.0f / lv[j];
  }
  #pragma unroll
  for (int r = 0; r < 16; ++r) {
    int qloc = w * 32 + (r & 3) + 8 * (r >> 2) + 4 * h5;
    int posg = i * Nn + q0 + qloc;
    float gpre = bf2f(g_all[((size_t)h * NPOS + posg) * 32 + ql]);
    float gate = 1.0f / (1.0f + __expf(-gpre));
    o_ws[(size_t)posg * Cc + h * DHh + ql] = f2bf(oacc[r] * inv[r] * gate);
  }
}

// ---------------------------------------------------------------------------
// Kernel 4: out = o_gated @ wo^T + bo via bf16 MFMA. M=128/block, N=128, K=128.
// ---------------------------------------------------------------------------
__global__ __launch_bounds__(256, 2) void k_out(const ushort_t* __restrict__ o_ws,
    const ushort_t* __restrict__ woT, const float* __restrict__ bo,
    float* __restrict__ out) {
  __shared__ ushort_t As[128 * 136];
  __shared__ ushort_t Bs[128 * 136];
  const int tid = threadIdx.x, lane = tid & 63, w = tid >> 6;
  const int q15 = lane & 15, quad = lane >> 4;
  const size_t m0 = (size_t)blockIdx.x * 128;

  #pragma unroll
  for (int r = 0; r < 8; ++r) {
    int idx = tid + 256 * r;
    int row = idx >> 4, seg = idx & 15;
    *(uint4*)&As[row * 136 + seg * 8] =
        *(const uint4*)&o_ws[(m0 + row) * 128 + seg * 8];
    *(uint4*)&Bs[row * 136 + seg * 8] =
        *(const uint4*)&woT[(size_t)row * 128 + seg * 8];
  }
  __syncthreads();

  f32x4 acc[2][8];
  #pragma unroll
  for (int mi = 0; mi < 2; ++mi)
    #pragma unroll
    for (int ni = 0; ni < 8; ++ni) {
      acc[mi][ni][0] = 0.f; acc[mi][ni][1] = 0.f;
      acc[mi][ni][2] = 0.f; acc[mi][ni][3] = 0.f;
    }
  #pragma unroll
  for (int kk = 0; kk < 4; ++kk) {
    bf16x8 a_[2];
    #pragma unroll
    for (int mi = 0; mi < 2; ++mi)
      a_[mi] = *(const bf16x8*)&As[(w * 32 + mi * 16 + q15) * 136 +
                                   kk * 32 + quad * 8];
    #pragma unroll
    for (int ni = 0; ni < 8; ++ni) {
      bf16x8 b_ = *(const bf16x8*)&Bs[(ni * 16 + q15) * 136 + kk * 32 + quad * 8];
      #pragma unroll
      for (int mi = 0; mi < 2; ++mi)
        acc[mi][ni] = __builtin_amdgcn_mfma_f32_16x16x32_bf16(
            a_[mi], b_, acc[mi][ni], 0, 0, 0);
    }
  }
  #pragma unroll
  for (int ni = 0; ni < 8; ++ni) {
    float bov = bo[ni * 16 + q15];
    #pragma unroll
    for (int mi = 0; mi < 2; ++mi)
      #pragma unroll
      for (int r = 0; r < 4; ++r) {
        int rowL = w * 32 + mi * 16 + quad * 4 + r;
        out[(m0 + rowL) * Cc + ni * 16 + q15] = acc[mi][ni][r] + bov;
      }
  }
}

// ---------------------------------------------------------------------------
extern "C" void kernel_launch(void* const* d_in, const int* in_sizes, int n_in,
                              void* d_out, int out_size, void* d_ws, size_t ws_size,
                              hipStream_t stream) {
  const float* x     = (const float*)d_in[0];
  const float* mask  = (const float*)d_in[1];
  const float* gamma = (const float*)d_in[2];
  const float* beta  = (const float*)d_in[3];
  const float* wb    = (const float*)d_in[4];
  const float* wq    = (const float*)d_in[5];
  const float* wk    = (const float*)d_in[6];
  const float* wv    = (const float*)d_in[7];
  const float* wg    = (const float*)d_in[8];
  const float* bg    = (const float*)d_in[9];
  const float* wo    = (const float*)d_in[10];
  const float* bo    = (const float*)d_in[11];
  float* out = (float*)d_out;

  char* ws = (char*)d_ws;
  ushort_t* xnb   = (ushort_t*)ws;                         // also o_ws (reused)
  ushort_t* qkvg  = (ushort_t*)(ws + (size_t)NPOS * 128 * 2);
  float*    biasT = (float*)(ws + (size_t)NPOS * 128 * 2
                                + (size_t)4 * NHh * NPOS * 32 * 2);
  ushort_t* wBt   = (ushort_t*)((char*)biasT + (size_t)NHh * NPOS * 4);
  ushort_t* woT   = wBt + 65536;
  ushort_t* o_ws  = xnb;   // xnb is dead after k_proj

  hipLaunchKernelGGL(k_wt, dim3(80), dim3(256), 0, stream,
                     wq, wk, wv, wg, wo, wBt, woT);
  hipLaunchKernelGGL(k_ln, dim3(NPOS / 4), dim3(256), 0, stream,
                     x, gamma, beta, wb, (unsigned int*)xnb, biasT);
  hipLaunchKernelGGL(k_proj, dim3(NPOS / 128), dim3(256), 0, stream,
                     xnb, wBt, bg, qkvg);
  hipLaunchKernelGGL(k_attn, dim3(12, Nn), dim3(256), 0, stream,
                     qkvg, biasT, mask, o_ws);
  hipLaunchKernelGGL(k_out, dim3(NPOS / 128), dim3(256), 0, stream,
                     o_ws, woT, bo, out);
}

// Round 2
// 386.094 us; speedup vs baseline: 1.1534x; 1.0167x over previous
//
#include <hip/hip_runtime.h>

#define Nn 384
#define Cc 128
#define DHh 32
#define NHh 4
#define NPOS (Nn*Nn)
#define LOG2E 1.4426950408889634f

typedef unsigned short ushort_t;
typedef __attribute__((ext_vector_type(8))) short bf16x8;
typedef __attribute__((ext_vector_type(4))) float f32x4;
typedef __attribute__((ext_vector_type(16))) float f32x16;
typedef __attribute__((ext_vector_type(2))) int i32x2;
typedef __attribute__((ext_vector_type(4))) int i32x4;

__device__ __forceinline__ ushort_t f2bf(float f) {
  union { float f; unsigned int u; } v; v.f = f;
  unsigned int r = v.u + 0x7fffu + ((v.u >> 16) & 1u);   // RNE
  return (ushort_t)(r >> 16);
}
__device__ __forceinline__ float bf2f(ushort_t u) {
  union { unsigned int u; float f; } v; v.u = ((unsigned int)u) << 16;
  return v.f;
}
__device__ __forceinline__ int cvt_pk_bf16(float a, float b) {
  int r;
  asm("v_cvt_pk_bf16_f32 %0, %1, %2" : "=v"(r) : "v"(a), "v"(b));
  return r;   // lo16 = bf16(a), hi16 = bf16(b)
}

// ---------------------------------------------------------------------------
// Kernel 0: wBt[512][128] bf16 = concat(wq,wk,wv,wg); q rows scaled by
// (1/sqrt(32))*log2e (exp2 softmax trick). woT[128][128] bf16 = wo cast.
// ---------------------------------------------------------------------------
__global__ __launch_bounds__(256) void k_wt(const float* __restrict__ wq,
    const float* __restrict__ wk, const float* __restrict__ wv,
    const float* __restrict__ wg, const float* __restrict__ wo,
    ushort_t* __restrict__ wBt, ushort_t* __restrict__ woT) {
  for (int rep = 0; rep < 4; ++rep) {
    int idx = blockIdx.x * 256 + threadIdx.x + rep * 20480;  // 80 blocks
    if (idx < 65536) {
      int c = idx >> 7, k = idx & 127;
      int mat = c >> 7, row = c & 127;
      const float* src;
      float scale = 1.0f;
      if (mat == 0)      { src = wq; scale = 0.17677669529663687f * LOG2E; }
      else if (mat == 1) { src = wk; }
      else if (mat == 2) { src = wv; }
      else               { src = wg; }
      wBt[idx] = f2bf(src[row * 128 + k] * scale);
    } else {
      int j = idx - 65536;
      woT[j] = f2bf(wo[j]);
    }
  }
}

// ---------------------------------------------------------------------------
// Kernel 1: LayerNorm (wave per position) -> xn bf16; triangle bias fp32 in
// BLOCKED-TRANSPOSED layout bias3[h][k>>2][q][k&3] (pre-scaled by log2e) so
// k_attn can C-init with float4 loads; mbias[i][k] = (mask-1)*1e9*log2e.
// ---------------------------------------------------------------------------
__global__ __launch_bounds__(256) void k_ln(const float* __restrict__ x,
    const float* __restrict__ gamma, const float* __restrict__ beta,
    const float* __restrict__ wb, const float* __restrict__ mask,
    unsigned int* __restrict__ xnb, float* __restrict__ bias3,
    float* __restrict__ mb_ws) {
  int wid = threadIdx.x >> 6, lane = threadIdx.x & 63;
  int p = blockIdx.x * 4 + wid;
  int i = p / Nn, j = p - i * Nn;
  size_t base = (size_t)p * Cc + lane * 2;
  float2 xv = *(const float2*)&x[base];
  float s = xv.x + xv.y;
  #pragma unroll
  for (int off = 1; off < 64; off <<= 1) s += __shfl_xor(s, off, 64);
  float mu = s * (1.0f / Cc);
  float d0 = xv.x - mu, d1 = xv.y - mu;
  float sq = d0 * d0 + d1 * d1;
  #pragma unroll
  for (int off = 1; off < 64; off <<= 1) sq += __shfl_xor(sq, off, 64);
  float rs = rsqrtf(sq * (1.0f / Cc) + 1e-5f);
  float2 g2 = *(const float2*)&gamma[lane * 2];
  float2 b2 = *(const float2*)&beta[lane * 2];
  float xn0 = d0 * rs * g2.x + b2.x;
  float xn1 = d1 * rs * g2.y + b2.y;
  unsigned int pack = (unsigned int)f2bf(xn0) | ((unsigned int)f2bf(xn1) << 16);
  xnb[(size_t)p * 64 + lane] = pack;
  #pragma unroll
  for (int h = 0; h < NHh; ++h) {
    float2 w2 = *(const float2*)&wb[h * Cc + lane * 2];
    float t = xn0 * w2.x + xn1 * w2.y;
    #pragma unroll
    for (int off = 1; off < 64; off <<= 1) t += __shfl_xor(t, off, 64);
    // bias3[h][j>>2][i][j&3]  (q = i is the row dim of scores, k = j)
    if (lane == 0)
      bias3[(size_t)h * NPOS + (size_t)(j >> 2) * (Nn * 4) + i * 4 + (j & 3)] =
          t * LOG2E;
  }
  if (lane == 1) mb_ws[p] = (mask[p] - 1.0f) * (1e9f * LOG2E);
}

// ---------------------------------------------------------------------------
// Kernel 2: projection GEMM via MFMA, looping all 8 n-chunks per block so the
// A-tile is staged and frag-loaded ONCE. Cs aliases Bs. LDS 53248 -> 3 blk/CU.
// ---------------------------------------------------------------------------
__global__ __launch_bounds__(256, 3) void k_proj(const ushort_t* __restrict__ xnb,
    const ushort_t* __restrict__ wBt, const float* __restrict__ bg,
    ushort_t* __restrict__ qkvg) {
  __shared__ __align__(16) char plds[34816 + 18432];
  ushort_t* As = (ushort_t*)plds;              // [128][136]
  ushort_t* Bs = (ushort_t*)(plds + 34816);    // [64][136]  (17408 B)
  ushort_t* Cs = (ushort_t*)(plds + 34816);    // [128][72]  (18432 B, alias)
  const int tid = threadIdx.x, lane = tid & 63, w = tid >> 6;
  const int q15 = lane & 15, quad = lane >> 4;
  const int m0 = blockIdx.x * 128;

  #pragma unroll
  for (int r = 0; r < 8; ++r) {
    int idx = tid + 256 * r;
    int row = idx >> 4, seg = idx & 15;
    *(uint4*)&As[row * 136 + seg * 8] =
        *(const uint4*)&xnb[(size_t)(m0 + row) * 128 + seg * 8];
  }
  __syncthreads();
  bf16x8 af[4][2];
  #pragma unroll
  for (int kk = 0; kk < 4; ++kk)
    #pragma unroll
    for (int mi = 0; mi < 2; ++mi)
      af[kk][mi] = *(const bf16x8*)&As[(w * 32 + mi * 16 + q15) * 136 +
                                       kk * 32 + quad * 8];

  for (int nb = 0; nb < 8; ++nb) {
    #pragma unroll
    for (int r = 0; r < 4; ++r) {
      int idx = tid + 256 * r;
      int row = idx >> 4, seg = idx & 15;
      *(uint4*)&Bs[row * 136 + seg * 8] =
          *(const uint4*)&wBt[(size_t)(nb * 64 + row) * 128 + seg * 8];
    }
    __syncthreads();

    f32x4 acc[2][4];
    #pragma unroll
    for (int mi = 0; mi < 2; ++mi)
      #pragma unroll
      for (int ni = 0; ni < 4; ++ni) {
        float init = 0.0f;
        if (nb >= 6) init = bg[(nb & 1) * 64 + ni * 16 + q15];
        acc[mi][ni][0] = init; acc[mi][ni][1] = init;
        acc[mi][ni][2] = init; acc[mi][ni][3] = init;
      }
    #pragma unroll
    for (int kk = 0; kk < 4; ++kk) {
      bf16x8 bf[4];
      #pragma unroll
      for (int ni = 0; ni < 4; ++ni)
        bf[ni] = *(const bf16x8*)&Bs[(ni * 16 + q15) * 136 + kk * 32 + quad * 8];
      #pragma unroll
      for (int mi = 0; mi < 2; ++mi)
        #pragma unroll
        for (int ni = 0; ni < 4; ++ni)
          acc[mi][ni] = __builtin_amdgcn_mfma_f32_16x16x32_bf16(
              af[kk][mi], bf[ni], acc[mi][ni], 0, 0, 0);
    }
    __syncthreads();                 // Bs frag reads done (Cs aliases Bs)
    #pragma unroll
    for (int mi = 0; mi < 2; ++mi)
      #pragma unroll
      for (int ni = 0; ni < 4; ++ni)
        #pragma unroll
        for (int r = 0; r < 4; ++r) {
          int rowL = w * 32 + mi * 16 + quad * 4 + r;
          Cs[rowL * 72 + ni * 16 + q15] = f2bf(acc[mi][ni][r]);
        }
    __syncthreads();
    const int mat = nb >> 1;
    #pragma unroll
    for (int r = 0; r < 4; ++r) {
      int idx = tid + 256 * r;
      int row = idx >> 3, seg = idx & 7;
      int cl = (nb & 1) * 64 + seg * 8;
      int hh = cl >> 5, dd = cl & 31;
      uint4 v = *(const uint4*)&Cs[row * 72 + seg * 8];
      *(uint4*)&qkvg[(size_t)mat * (NHh * (size_t)NPOS * 32) +
                     (size_t)hh * ((size_t)NPOS * 32) +
                     (size_t)(m0 + row) * 32 + dd] = v;
    }
    __syncthreads();                 // Cs reads done before next Bs stage
  }
}

// ---------------------------------------------------------------------------
// Kernel 3: swapped-operand 32x32 MFMA flash attention, softmax fully in
// registers.  S^T = mfma(K,Q); P via v_cvt_pk_bf16_f32 + permlane32_swap
// (no P LDS round trip).  C-init now uses the blocked-transposed bias3
// layout + precomputed mbias: 8 float4 loads per t-tile instead of 32
// scalar loads.  K/V^T double-buffered in XOR-swizzled LDS; 1 barrier/chunk.
// ---------------------------------------------------------------------------
__global__ __launch_bounds__(256, 4) void k_attn(const ushort_t* __restrict__ qkvg,
    const float* __restrict__ bias3, const float* __restrict__ mb_ws,
    ushort_t* __restrict__ o_ws) {
  __shared__ __align__(16) char lds[33280];
  ushort_t* KsB = (ushort_t*)lds;              // 2 x [128][32] (8192 B each)
  ushort_t* VtB = (ushort_t*)(lds + 16384);    // 2 x [32][128] (8192 B each)
  float*  lsmem = (float*)(lds + 32768);       // [128] row sums (per-wave 32)

  const int tid = threadIdx.x, lane = tid & 63, w = tid >> 6;
  const int ql = lane & 31, h5 = lane >> 5;
  const int h  = blockIdx.x / 3;
  const int qt = blockIdx.x % 3;
  const int i  = blockIdx.y;
  const int q0 = qt * 128;

  const ushort_t* q_all = qkvg;
  const ushort_t* k_all = qkvg + (size_t)1 * NHh * NPOS * 32;
  const ushort_t* v_all = qkvg + (size_t)2 * NHh * NPOS * 32;
  const ushort_t* g_all = qkvg + (size_t)3 * NHh * NPOS * 32;
  const size_t hbase = ((size_t)h * NPOS + (size_t)i * Nn) * 32;
  const float* brow = bias3 + (size_t)h * NPOS;   // [k>>2][q][k&3], *log2e
  const float* mrow = mb_ws + (size_t)i * Nn;     // (mask-1)*1e9*log2e

  const int qglob = q0 + w * 32 + ql;
  // Q fragments direct from global (once per block; L2-resident)
  const ushort_t* qp = q_all + hbase + (size_t)qglob * 32;
  const bf16x8 qf0 = *(const bf16x8*)&qp[h5 * 8];        // ch  0..15 half
  const bf16x8 qf1 = *(const bf16x8*)&qp[16 + h5 * 8];   // ch 16..31 half

  f32x16 oacc;
  #pragma unroll
  for (int r = 0; r < 16; ++r) oacc[r] = 0.f;
  float lsum = 0.f;

  const int swk = (ql >> 1) & 3;   // K-tile seg swizzle (read side)
  const int swv = (ql >> 1) & 7;   // V^T k-block swizzle (read side)

  for (int ch = 0; ch < 3; ++ch) {
    const int kbase = ch * 128;
    ushort_t* Ksb = KsB + (ch & 1) * 4096;
    ushort_t* Vtb = VtB + (ch & 1) * 4096;
    // ---- stage K chunk [128][32], seg ^= (row>>1)&3  (bank-conflict-free)
    #pragma unroll
    for (int r = 0; r < 2; ++r) {
      int idx = tid + 256 * r;
      int row = idx >> 2, seg = idx & 3;
      *(uint4*)&Ksb[row * 32 + (seg ^ ((row >> 1) & 3)) * 8] =
          *(const uint4*)&k_all[hbase + (size_t)(kbase + row) * 32 + seg * 8];
    }
    // ---- stage V^T [32 d][128 k] via dword-wide 2x2 transpose,
    //      k-block ^= (d>>1)&7  (2-way max on store & read)
    #pragma unroll
    for (int r = 0; r < 4; ++r) {
      int idx = tid + 256 * r;
      int dp = idx & 15, kp = idx >> 4;
      unsigned int a0 = *(const unsigned int*)
          &v_all[hbase + (size_t)(kbase + 2 * kp) * 32 + dp * 2];
      unsigned int a1 = *(const unsigned int*)
          &v_all[hbase + (size_t)(kbase + 2 * kp + 1) * 32 + dp * 2];
      unsigned int lo = (a0 & 0xffffu) | (a1 << 16);   // d=2dp   : k, k+1
      unsigned int hi = (a0 >> 16) | (a1 & 0xffff0000u); // d=2dp+1
      unsigned int* v32 = (unsigned int*)Vtb;
      int col = ((kp >> 2) ^ (dp & 7)) * 4 + (kp & 3);
      v32[(2 * dp) * 64 + col] = lo;
      v32[(2 * dp + 1) * 64 + col] = hi;
    }
    __syncthreads();   // only barrier in the chunk (dbuf covers the rest)

    #pragma unroll
    for (int t = 0; t < 4; ++t) {
      // K fragments: rows = k (lane&31), elems = channel half
      bf16x8 kf0 = *(const bf16x8*)&Ksb[(t * 32 + ql) * 32 + ((h5)     ^ swk) * 8];
      bf16x8 kf1 = *(const bf16x8*)&Ksb[(t * 32 + ql) * 32 + ((2 + h5) ^ swk) * 8];
      // C-init = tri_bias (float4 over 4 consecutive k) + mask bias (float4)
      const int K0 = kbase + t * 32 + 4 * h5;
      f32x16 acc;
      #pragma unroll
      for (int g = 0; g < 4; ++g) {
        f32x4 b4 = *(const f32x4*)
            &brow[(size_t)((K0 >> 2) + 2 * g) * (Nn * 4) + qglob * 4];
        f32x4 m4 = *(const f32x4*)&mrow[K0 + 8 * g];
        acc[4 * g + 0] = b4[0] + m4[0];
        acc[4 * g + 1] = b4[1] + m4[1];
        acc[4 * g + 2] = b4[2] + m4[2];
        acc[4 * g + 3] = b4[3] + m4[3];
      }
      // S^T = K Q^T + C   (rows = k in reg pattern, cols = q = lane&31)
      acc = __builtin_amdgcn_mfma_f32_32x32x16_bf16(kf0, qf0, acc, 0, 0, 0);
      acc = __builtin_amdgcn_mfma_f32_32x32x16_bf16(kf1, qf1, acc, 0, 0, 0);
      // softmax in registers: exp2 (inputs pre-scaled), in-lane row sums,
      // packed bf16:  pk[r>>1] = {P[k], P[k+1]}
      int pk[8];
      #pragma unroll
      for (int r = 0; r < 16; r += 2) {
        float e0 = exp2f(acc[r]);
        float e1 = exp2f(acc[r + 1]);
        lsum += e0 + e1;
        pk[r >> 1] = cvt_pk_bf16(e0, e1);
      }
      // PV for k-slices kt = 2t, 2t+1: assemble pa via permlane32_swap.
      //  swap(pk[4b],pk[4b+2]) -> (pa.d0, pa.d2); (+1,+3) -> (d1, d3)
      #pragma unroll
      for (int b2 = 0; b2 < 2; ++b2) {
        i32x2 s0 = __builtin_amdgcn_permlane32_swap(pk[4 * b2 + 0],
                                                    pk[4 * b2 + 2], false, false);
        i32x2 s1 = __builtin_amdgcn_permlane32_swap(pk[4 * b2 + 1],
                                                    pk[4 * b2 + 3], false, false);
        union { i32x4 i; bf16x8 b; } pu;
        pu.i[0] = s0[0]; pu.i[1] = s1[0]; pu.i[2] = s0[1]; pu.i[3] = s1[1];
        int kt = 2 * t + b2;
        bf16x8 vb = *(const bf16x8*)
            &Vtb[ql * 128 + ((2 * kt + h5) ^ swv) * 8];
        oacc = __builtin_amdgcn_mfma_f32_32x32x16_bf16(pu.b, vb, oacc, 0, 0, 0);
      }
    }
  }

  // epilogue: complete row sums (partner half holds complementary k set),
  // broadcast per-wave via LDS, normalize, gate, store o_gated bf16.
  float lsf = lsum + __shfl_xor(lsum, 32, 64);
  if (lane < 32) lsmem[w * 32 + ql] = lsf;
  float inv[16];
  #pragma unroll
  for (int g = 0; g < 4; ++g) {
    f32x4 lv = *(const f32x4*)&lsmem[w * 32 + g * 8 + 4 * h5];
    #pragma unroll
    for (int j = 0; j < 4; ++j) inv[g * 4 + j] = 1.0f / lv[j];
  }
  #pragma unroll
  for (int r = 0; r < 16; ++r) {
    int qloc = w * 32 + (r & 3) + 8 * (r >> 2) + 4 * h5;
    int posg = i * Nn + q0 + qloc;
    float gpre = bf2f(g_all[((size_t)h * NPOS + posg) * 32 + ql]);
    float gate = 1.0f / (1.0f + __expf(-gpre));
    o_ws[(size_t)posg * Cc + h * DHh + ql] = f2bf(oacc[r] * inv[r] * gate);
  }
}

// ---------------------------------------------------------------------------
// Kernel 4: out = o_gated @ wo^T + bo via bf16 MFMA. M=128/block, N=128, K=128.
// ---------------------------------------------------------------------------
__global__ __launch_bounds__(256, 2) void k_out(const ushort_t* __restrict__ o_ws,
    const ushort_t* __restrict__ woT, const float* __restrict__ bo,
    float* __restrict__ out) {
  __shared__ ushort_t As[128 * 136];
  __shared__ ushort_t Bs[128 * 136];
  const int tid = threadIdx.x, lane = tid & 63, w = tid >> 6;
  const int q15 = lane & 15, quad = lane >> 4;
  const size_t m0 = (size_t)blockIdx.x * 128;

  #pragma unroll
  for (int r = 0; r < 8; ++r) {
    int idx = tid + 256 * r;
    int row = idx >> 4, seg = idx & 15;
    *(uint4*)&As[row * 136 + seg * 8] =
        *(const uint4*)&o_ws[(m0 + row) * 128 + seg * 8];
    *(uint4*)&Bs[row * 136 + seg * 8] =
        *(const uint4*)&woT[(size_t)row * 128 + seg * 8];
  }
  __syncthreads();

  f32x4 acc[2][8];
  #pragma unroll
  for (int mi = 0; mi < 2; ++mi)
    #pragma unroll
    for (int ni = 0; ni < 8; ++ni) {
      acc[mi][ni][0] = 0.f; acc[mi][ni][1] = 0.f;
      acc[mi][ni][2] = 0.f; acc[mi][ni][3] = 0.f;
    }
  #pragma unroll
  for (int kk = 0; kk < 4; ++kk) {
    bf16x8 a_[2];
    #pragma unroll
    for (int mi = 0; mi < 2; ++mi)
      a_[mi] = *(const bf16x8*)&As[(w * 32 + mi * 16 + q15) * 136 +
                                   kk * 32 + quad * 8];
    #pragma unroll
    for (int ni = 0; ni < 8; ++ni) {
      bf16x8 b_ = *(const bf16x8*)&Bs[(ni * 16 + q15) * 136 + kk * 32 + quad * 8];
      #pragma unroll
      for (int mi = 0; mi < 2; ++mi)
        acc[mi][ni] = __builtin_amdgcn_mfma_f32_16x16x32_bf16(
            a_[mi], b_, acc[mi][ni], 0, 0, 0);
    }
  }
  #pragma unroll
  for (int ni = 0; ni < 8; ++ni) {
    float bov = bo[ni * 16 + q15];
    #pragma unroll
    for (int mi = 0; mi < 2; ++mi)
      #pragma unroll
      for (int r = 0; r < 4; ++r) {
        int rowL = w * 32 + mi * 16 + quad * 4 + r;
        out[(m0 + rowL) * Cc + ni * 16 + q15] = acc[mi][ni][r] + bov;
      }
  }
}

// ---------------------------------------------------------------------------
extern "C" void kernel_launch(void* const* d_in, const int* in_sizes, int n_in,
                              void* d_out, int out_size, void* d_ws, size_t ws_size,
                              hipStream_t stream) {
  const float* x     = (const float*)d_in[0];
  const float* mask  = (const float*)d_in[1];
  const float* gamma = (const float*)d_in[2];
  const float* beta  = (const float*)d_in[3];
  const float* wb    = (const float*)d_in[4];
  const float* wq    = (const float*)d_in[5];
  const float* wk    = (const float*)d_in[6];
  const float* wv    = (const float*)d_in[7];
  const float* wg    = (const float*)d_in[8];
  const float* bg    = (const float*)d_in[9];
  const float* wo    = (const float*)d_in[10];
  const float* bo    = (const float*)d_in[11];
  float* out = (float*)d_out;

  char* ws = (char*)d_ws;
  ushort_t* xnb   = (ushort_t*)ws;                         // also o_ws (reused)
  ushort_t* qkvg  = (ushort_t*)(ws + (size_t)NPOS * 128 * 2);
  float*    bias3 = (float*)(ws + (size_t)NPOS * 128 * 2
                                + (size_t)4 * NHh * NPOS * 32 * 2);
  ushort_t* wBt   = (ushort_t*)((char*)bias3 + (size_t)NHh * NPOS * 4);
  ushort_t* woT   = wBt + 65536;
  float*    mb_ws = (float*)(woT + 16384);
  ushort_t* o_ws  = xnb;   // xnb is dead after k_proj

  hipLaunchKernelGGL(k_wt, dim3(80), dim3(256), 0, stream,
                     wq, wk, wv, wg, wo, wBt, woT);
  hipLaunchKernelGGL(k_ln, dim3(NPOS / 4), dim3(256), 0, stream,
                     x, gamma, beta, wb, mask, (unsigned int*)xnb, bias3, mb_ws);
  hipLaunchKernelGGL(k_proj, dim3(NPOS / 128), dim3(256), 0, stream,
                     xnb, wBt, bg, qkvg);
  hipLaunchKernelGGL(k_attn, dim3(12, Nn), dim3(256), 0, stream,
                     qkvg, bias3, mb_ws, o_ws);
  hipLaunchKernelGGL(k_out, dim3(NPOS / 128), dim3(256), 0, stream,
                     o_ws, woT, bo, out);
}

// Round 3
// 372.573 us; speedup vs baseline: 1.1953x; 1.0363x over previous
//
#include <hip/hip_runtime.h>

#define Nn 384
#define Cc 128
#define DHh 32
#define NHh 4
#define NPOS (Nn*Nn)
#define LOG2E 1.4426950408889634f

typedef unsigned short ushort_t;
typedef __attribute__((ext_vector_type(8))) short bf16x8;
typedef __attribute__((ext_vector_type(4))) float f32x4;
typedef __attribute__((ext_vector_type(16))) float f32x16;
typedef __attribute__((ext_vector_type(2))) int i32x2;
typedef __attribute__((ext_vector_type(4))) int i32x4;

__device__ __forceinline__ ushort_t f2bf(float f) {
  union { float f; unsigned int u; } v; v.f = f;
  unsigned int r = v.u + 0x7fffu + ((v.u >> 16) & 1u);   // RNE
  return (ushort_t)(r >> 16);
}
__device__ __forceinline__ float bf2f(ushort_t u) {
  union { unsigned int u; float f; } v; v.u = ((unsigned int)u) << 16;
  return v.f;
}
__device__ __forceinline__ int cvt_pk_bf16(float a, float b) {
  int r;
  asm("v_cvt_pk_bf16_f32 %0, %1, %2" : "=v"(r) : "v"(a), "v"(b));
  return r;   // lo16 = bf16(a), hi16 = bf16(b)
}

// ---------------------------------------------------------------------------
// Kernel 0: wBt[512][128] bf16 = concat(wq,wk,wv,wg); q rows scaled by
// (1/sqrt(32))*log2e (exp2 softmax trick). woT[128][128] bf16 = wo cast.
// ---------------------------------------------------------------------------
__global__ __launch_bounds__(256) void k_wt(const float* __restrict__ wq,
    const float* __restrict__ wk, const float* __restrict__ wv,
    const float* __restrict__ wg, const float* __restrict__ wo,
    ushort_t* __restrict__ wBt, ushort_t* __restrict__ woT) {
  for (int rep = 0; rep < 4; ++rep) {
    int idx = blockIdx.x * 256 + threadIdx.x + rep * 20480;  // 80 blocks
    if (idx < 65536) {
      int c = idx >> 7, k = idx & 127;
      int mat = c >> 7, row = c & 127;
      const float* src;
      float scale = 1.0f;
      if (mat == 0)      { src = wq; scale = 0.17677669529663687f * LOG2E; }
      else if (mat == 1) { src = wk; }
      else if (mat == 2) { src = wv; }
      else               { src = wg; }
      wBt[idx] = f2bf(src[row * 128 + k] * scale);
    } else {
      int j = idx - 65536;
      woT[j] = f2bf(wo[j]);
    }
  }
}

// ---------------------------------------------------------------------------
// Kernel 1: LayerNorm (wave per position) -> xn bf16; triangle bias fp32 in
// BLOCKED-TRANSPOSED layout bias3[h][k>>2][q][k&3] (pre-scaled by log2e) so
// k_attn can C-init with float4 loads; mbias[i][k] = (mask-1)*1e9*log2e.
// ---------------------------------------------------------------------------
__global__ __launch_bounds__(256) void k_ln(const float* __restrict__ x,
    const float* __restrict__ gamma, const float* __restrict__ beta,
    const float* __restrict__ wb, const float* __restrict__ mask,
    unsigned int* __restrict__ xnb, float* __restrict__ bias3,
    float* __restrict__ mb_ws) {
  int wid = threadIdx.x >> 6, lane = threadIdx.x & 63;
  int p = blockIdx.x * 4 + wid;
  int i = p / Nn, j = p - i * Nn;
  size_t base = (size_t)p * Cc + lane * 2;
  float2 xv = *(const float2*)&x[base];
  float s = xv.x + xv.y;
  #pragma unroll
  for (int off = 1; off < 64; off <<= 1) s += __shfl_xor(s, off, 64);
  float mu = s * (1.0f / Cc);
  float d0 = xv.x - mu, d1 = xv.y - mu;
  float sq = d0 * d0 + d1 * d1;
  #pragma unroll
  for (int off = 1; off < 64; off <<= 1) sq += __shfl_xor(sq, off, 64);
  float rs = rsqrtf(sq * (1.0f / Cc) + 1e-5f);
  float2 g2 = *(const float2*)&gamma[lane * 2];
  float2 b2 = *(const float2*)&beta[lane * 2];
  float xn0 = d0 * rs * g2.x + b2.x;
  float xn1 = d1 * rs * g2.y + b2.y;
  unsigned int pack = (unsigned int)f2bf(xn0) | ((unsigned int)f2bf(xn1) << 16);
  xnb[(size_t)p * 64 + lane] = pack;
  #pragma unroll
  for (int h = 0; h < NHh; ++h) {
    float2 w2 = *(const float2*)&wb[h * Cc + lane * 2];
    float t = xn0 * w2.x + xn1 * w2.y;
    #pragma unroll
    for (int off = 1; off < 64; off <<= 1) t += __shfl_xor(t, off, 64);
    // bias3[h][j>>2][i][j&3]  (q = i is the row dim of scores, k = j)
    if (lane == 0)
      bias3[(size_t)h * NPOS + (size_t)(j >> 2) * (Nn * 4) + i * 4 + (j & 3)] =
          t * LOG2E;
  }
  if (lane == 1) mb_ws[p] = (mask[p] - 1.0f) * (1e9f * LOG2E);
}

// ---------------------------------------------------------------------------
// Kernel 2: projection GEMM via MFMA, looping all 8 n-chunks per block so the
// A-tile is staged and frag-loaded ONCE. Cs aliases Bs. LDS 53248 -> 3 blk/CU.
// ---------------------------------------------------------------------------
__global__ __launch_bounds__(256, 3) void k_proj(const ushort_t* __restrict__ xnb,
    const ushort_t* __restrict__ wBt, const float* __restrict__ bg,
    ushort_t* __restrict__ qkvg) {
  __shared__ __align__(16) char plds[34816 + 18432];
  ushort_t* As = (ushort_t*)plds;              // [128][136]
  ushort_t* Bs = (ushort_t*)(plds + 34816);    // [64][136]  (17408 B)
  ushort_t* Cs = (ushort_t*)(plds + 34816);    // [128][72]  (18432 B, alias)
  const int tid = threadIdx.x, lane = tid & 63, w = tid >> 6;
  const int q15 = lane & 15, quad = lane >> 4;
  const int m0 = blockIdx.x * 128;

  #pragma unroll
  for (int r = 0; r < 8; ++r) {
    int idx = tid + 256 * r;
    int row = idx >> 4, seg = idx & 15;
    *(uint4*)&As[row * 136 + seg * 8] =
        *(const uint4*)&xnb[(size_t)(m0 + row) * 128 + seg * 8];
  }
  __syncthreads();
  bf16x8 af[4][2];
  #pragma unroll
  for (int kk = 0; kk < 4; ++kk)
    #pragma unroll
    for (int mi = 0; mi < 2; ++mi)
      af[kk][mi] = *(const bf16x8*)&As[(w * 32 + mi * 16 + q15) * 136 +
                                       kk * 32 + quad * 8];

  for (int nb = 0; nb < 8; ++nb) {
    #pragma unroll
    for (int r = 0; r < 4; ++r) {
      int idx = tid + 256 * r;
      int row = idx >> 4, seg = idx & 15;
      *(uint4*)&Bs[row * 136 + seg * 8] =
          *(const uint4*)&wBt[(size_t)(nb * 64 + row) * 128 + seg * 8];
    }
    __syncthreads();

    f32x4 acc[2][4];
    #pragma unroll
    for (int mi = 0; mi < 2; ++mi)
      #pragma unroll
      for (int ni = 0; ni < 4; ++ni) {
        float init = 0.0f;
        if (nb >= 6) init = bg[(nb & 1) * 64 + ni * 16 + q15];
        acc[mi][ni][0] = init; acc[mi][ni][1] = init;
        acc[mi][ni][2] = init; acc[mi][ni][3] = init;
      }
    #pragma unroll
    for (int kk = 0; kk < 4; ++kk) {
      bf16x8 bf[4];
      #pragma unroll
      for (int ni = 0; ni < 4; ++ni)
        bf[ni] = *(const bf16x8*)&Bs[(ni * 16 + q15) * 136 + kk * 32 + quad * 8];
      #pragma unroll
      for (int mi = 0; mi < 2; ++mi)
        #pragma unroll
        for (int ni = 0; ni < 4; ++ni)
          acc[mi][ni] = __builtin_amdgcn_mfma_f32_16x16x32_bf16(
              af[kk][mi], bf[ni], acc[mi][ni], 0, 0, 0);
    }
    __syncthreads();                 // Bs frag reads done (Cs aliases Bs)
    #pragma unroll
    for (int mi = 0; mi < 2; ++mi)
      #pragma unroll
      for (int ni = 0; ni < 4; ++ni)
        #pragma unroll
        for (int r = 0; r < 4; ++r) {
          int rowL = w * 32 + mi * 16 + quad * 4 + r;
          Cs[rowL * 72 + ni * 16 + q15] = f2bf(acc[mi][ni][r]);
        }
    __syncthreads();
    const int mat = nb >> 1;
    #pragma unroll
    for (int r = 0; r < 4; ++r) {
      int idx = tid + 256 * r;
      int row = idx >> 3, seg = idx & 7;
      int cl = (nb & 1) * 64 + seg * 8;
      int hh = cl >> 5, dd = cl & 31;
      uint4 v = *(const uint4*)&Cs[row * 72 + seg * 8];
      *(uint4*)&qkvg[(size_t)mat * (NHh * (size_t)NPOS * 32) +
                     (size_t)hh * ((size_t)NPOS * 32) +
                     (size_t)(m0 + row) * 32 + dd] = v;
    }
    __syncthreads();                 // Cs reads done before next Bs stage
  }
}

// ---------------------------------------------------------------------------
// Kernel 3: swapped-operand 32x32 MFMA flash attention, softmax fully in
// registers.  Fully-unrolled chunk loop: all bias/mask/staging addresses fold
// to base+imm.  T14 pipeline: next chunk's K/V global loads issued before the
// barrier; next tile's bias float4s prefetched right after current consume
// (crosses the barrier too).  lsmem aliases the parity-1 V buffer -> LDS
// 32768 B -> up to 5 blocks/CU.
// ---------------------------------------------------------------------------
__global__ __launch_bounds__(256, 4) void k_attn(const ushort_t* __restrict__ qkvg,
    const float* __restrict__ bias3, const float* __restrict__ mb_ws,
    ushort_t* __restrict__ o_ws) {
  __shared__ __align__(16) char lds[32768];
  ushort_t* KsB = (ushort_t*)lds;              // 2 x [128][32] (8192 B each)
  ushort_t* VtB = (ushort_t*)(lds + 16384);    // 2 x [32][128] (8192 B each)
  float*  lsmem = (float*)(lds + 24576);       // alias parity-1 V buf (epilogue)

  const int tid = threadIdx.x, lane = tid & 63, w = tid >> 6;
  const int ql = lane & 31, h5 = lane >> 5;
  const int h  = blockIdx.x / 3;
  const int qt = blockIdx.x % 3;
  const int i  = blockIdx.y;
  const int q0 = qt * 128;

  const ushort_t* q_all = qkvg;
  const ushort_t* k_all = qkvg + (size_t)1 * NHh * NPOS * 32;
  const ushort_t* v_all = qkvg + (size_t)2 * NHh * NPOS * 32;
  const ushort_t* g_all = qkvg + (size_t)3 * NHh * NPOS * 32;
  const size_t hbase = ((size_t)h * NPOS + (size_t)i * Nn) * 32;
  const int qglob = q0 + w * 32 + ql;

  // all tile addressing below = these bases + compile-time constants
  const float* bptr = bias3 + (size_t)h * NPOS + (size_t)h5 * (Nn * 4) + qglob * 4;
  const float* mptr = mb_ws + (size_t)i * Nn + 4 * h5;

  // Q fragments direct from global (once per block; L2-resident)
  const ushort_t* qp = q_all + hbase + (size_t)qglob * 32;
  const bf16x8 qf0 = *(const bf16x8*)&qp[h5 * 8];        // ch  0..15 half
  const bf16x8 qf1 = *(const bf16x8*)&qp[16 + h5 * 8];   // ch 16..31 half

  // staging decomposition (constant per thread)
  const int krow0 = tid >> 2, kseg = tid & 3;    // K: rows krow0, krow0+64
  const int vdp = tid & 15, vkp0 = tid >> 4;     // V: kp = vkp0 + 16*r

  f32x16 oacc;
  #pragma unroll
  for (int r = 0; r < 16; ++r) oacc[r] = 0.f;
  float lsum = 0.f;
  const int swk = (ql >> 1) & 3;   // K-tile seg swizzle (read side)
  const int swv = (ql >> 1) & 7;   // V^T k-block swizzle (read side)

  uint4 kv0, kv1;                  // K staging regs (in flight across compute)
  unsigned int va[8];              // V staging regs
  f32x4 bb0, bb1, bb2, bb3;        // bias prefetch regs

#define KV_ISSUE(CH) do {                                                     \
    const size_t kb = hbase + (size_t)((CH) * 128) * 32;                      \
    kv0 = *(const uint4*)&k_all[kb + (size_t)krow0 * 32 + kseg * 8];          \
    kv1 = *(const uint4*)&k_all[kb + (size_t)(krow0 + 64) * 32 + kseg * 8];   \
    _Pragma("unroll")                                                         \
    for (int r = 0; r < 4; ++r) {                                             \
      va[2*r+0] = *(const unsigned int*)                                      \
          &v_all[kb + (size_t)(vkp0 + 16*r) * 64 + vdp * 2];                  \
      va[2*r+1] = *(const unsigned int*)                                      \
          &v_all[kb + (size_t)(vkp0 + 16*r) * 64 + 32 + vdp * 2];             \
    }                                                                         \
  } while (0)

#define KV_WRITE(CH) do {                                                     \
    ushort_t* Ksb_ = KsB + ((CH) & 1) * 4096;                                 \
    unsigned int* v32_ = (unsigned int*)(VtB + ((CH) & 1) * 4096);            \
    *(uint4*)&Ksb_[krow0 * 32 + (kseg ^ ((krow0 >> 1) & 3)) * 8] = kv0;       \
    *(uint4*)&Ksb_[(krow0 + 64) * 32 +                                        \
                   (kseg ^ (((krow0 + 64) >> 1) & 3)) * 8] = kv1;             \
    _Pragma("unroll")                                                         \
    for (int r = 0; r < 4; ++r) {                                             \
      int kp_ = vkp0 + 16 * r;                                                \
      unsigned int a0 = va[2*r], a1 = va[2*r+1];                              \
      unsigned int lo = (a0 & 0xffffu) | (a1 << 16);                          \
      unsigned int hi = (a0 >> 16) | (a1 & 0xffff0000u);                      \
      int col_ = ((kp_ >> 2) ^ (vdp & 7)) * 4 + (kp_ & 3);                    \
      v32_[(2 * vdp) * 64 + col_] = lo;                                       \
      v32_[(2 * vdp + 1) * 64 + col_] = hi;                                   \
    }                                                                         \
  } while (0)

#define BIAS_LOAD(CH, T) do {                                                 \
    bb0 = *(const f32x4*)&bptr[((CH) * 32 + (T) * 8 + 0) * (Nn * 4)];         \
    bb1 = *(const f32x4*)&bptr[((CH) * 32 + (T) * 8 + 2) * (Nn * 4)];         \
    bb2 = *(const f32x4*)&bptr[((CH) * 32 + (T) * 8 + 4) * (Nn * 4)];         \
    bb3 = *(const f32x4*)&bptr[((CH) * 32 + (T) * 8 + 6) * (Nn * 4)];         \
  } while (0)

#define TILE(CH, T, PF, NCH, NT) do {                                         \
    ushort_t* Ksb_ = KsB + ((CH) & 1) * 4096;                                 \
    ushort_t* Vtb_ = VtB + ((CH) & 1) * 4096;                                 \
    bf16x8 kf0 = *(const bf16x8*)                                             \
        &Ksb_[((T) * 32 + ql) * 32 + ((0 + h5) ^ swk) * 8];                   \
    bf16x8 kf1 = *(const bf16x8*)                                             \
        &Ksb_[((T) * 32 + ql) * 32 + ((2 + h5) ^ swk) * 8];                   \
    f32x4 m0_ = *(const f32x4*)&mptr[(CH) * 128 + (T) * 32 + 0];              \
    f32x4 m1_ = *(const f32x4*)&mptr[(CH) * 128 + (T) * 32 + 8];              \
    f32x4 m2_ = *(const f32x4*)&mptr[(CH) * 128 + (T) * 32 + 16];             \
    f32x4 m3_ = *(const f32x4*)&mptr[(CH) * 128 + (T) * 32 + 24];             \
    f32x16 acc;                                                               \
    _Pragma("unroll")                                                         \
    for (int j = 0; j < 4; ++j) {                                             \
      acc[0  + j] = bb0[j] + m0_[j];                                          \
      acc[4  + j] = bb1[j] + m1_[j];                                          \
      acc[8  + j] = bb2[j] + m2_[j];                                          \
      acc[12 + j] = bb3[j] + m3_[j];                                          \
    }                                                                         \
    if (PF) BIAS_LOAD(NCH, NT);          /* prefetch next tile's bias */      \
    acc = __builtin_amdgcn_mfma_f32_32x32x16_bf16(kf0, qf0, acc, 0, 0, 0);    \
    acc = __builtin_amdgcn_mfma_f32_32x32x16_bf16(kf1, qf1, acc, 0, 0, 0);    \
    int pk[8];                                                                \
    _Pragma("unroll")                                                         \
    for (int r = 0; r < 16; r += 2) {                                         \
      float e0 = exp2f(acc[r]);                                               \
      float e1 = exp2f(acc[r + 1]);                                           \
      lsum += e0 + e1;                                                        \
      pk[r >> 1] = cvt_pk_bf16(e0, e1);                                       \
    }                                                                         \
    _Pragma("unroll")                                                         \
    for (int b2 = 0; b2 < 2; ++b2) {                                          \
      i32x2 s0 = __builtin_amdgcn_permlane32_swap(pk[4*b2+0], pk[4*b2+2],     \
                                                  false, false);              \
      i32x2 s1 = __builtin_amdgcn_permlane32_swap(pk[4*b2+1], pk[4*b2+3],     \
                                                  false, false);              \
      union { i32x4 i; bf16x8 b; } pu;                                        \
      pu.i[0] = s0[0]; pu.i[1] = s1[0]; pu.i[2] = s0[1]; pu.i[3] = s1[1];     \
      bf16x8 vb = *(const bf16x8*)                                            \
          &Vtb_[ql * 128 + ((2 * (2*(T)+b2) + h5) ^ swv) * 8];                \
      oacc = __builtin_amdgcn_mfma_f32_32x32x16_bf16(pu.b, vb, oacc, 0,0,0);  \
    }                                                                         \
  } while (0)

  // ---- pipelined, fully-unrolled main body (3 chunks x 4 tiles) ----
  KV_ISSUE(0);
  BIAS_LOAD(0, 0);
  KV_WRITE(0);
  KV_ISSUE(1);
  __syncthreads();
  TILE(0,0, 1, 0,1); TILE(0,1, 1, 0,2); TILE(0,2, 1, 0,3); TILE(0,3, 1, 1,0);
  KV_WRITE(1);
  KV_ISSUE(2);
  __syncthreads();
  TILE(1,0, 1, 1,1); TILE(1,1, 1, 1,2); TILE(1,2, 1, 1,3); TILE(1,3, 1, 2,0);
  KV_WRITE(2);
  __syncthreads();
  TILE(2,0, 1, 2,1); TILE(2,1, 1, 2,2); TILE(2,2, 1, 2,3); TILE(2,3, 0, 0,0);

#undef KV_ISSUE
#undef KV_WRITE
#undef BIAS_LOAD
#undef TILE

  // epilogue: complete row sums (partner half holds complementary k set),
  // broadcast per-wave via LDS (safe: per-wave region, parity-1 V buf dead),
  // normalize, gate, store o_gated bf16.
  float lsf = lsum + __shfl_xor(lsum, 32, 64);
  if (lane < 32) lsmem[w * 32 + ql] = lsf;
  float inv[16];
  #pragma unroll
  for (int g = 0; g < 4; ++g) {
    f32x4 lv = *(const f32x4*)&lsmem[w * 32 + g * 8 + 4 * h5];
    #pragma unroll
    for (int j = 0; j < 4; ++j) inv[g * 4 + j] = 1.0f / lv[j];
  }
  #pragma unroll
  for (int r = 0; r < 16; ++r) {
    int qloc = w * 32 + (r & 3) + 8 * (r >> 2) + 4 * h5;
    int posg = i * Nn + q0 + qloc;
    float gpre = bf2f(g_all[((size_t)h * NPOS + posg) * 32 + ql]);
    float gate = 1.0f / (1.0f + __expf(-gpre));
    o_ws[(size_t)posg * Cc + h * DHh + ql] = f2bf(oacc[r] * inv[r] * gate);
  }
}

// ---------------------------------------------------------------------------
// Kernel 4: out = o_gated @ wo^T + bo via bf16 MFMA. M=128/block, N=128, K=128.
// ---------------------------------------------------------------------------
__global__ __launch_bounds__(256, 2) void k_out(const ushort_t* __restrict__ o_ws,
    const ushort_t* __restrict__ woT, const float* __restrict__ bo,
    float* __restrict__ out) {
  __shared__ ushort_t As[128 * 136];
  __shared__ ushort_t Bs[128 * 136];
  const int tid = threadIdx.x, lane = tid & 63, w = tid >> 6;
  const int q15 = lane & 15, quad = lane >> 4;
  const size_t m0 = (size_t)blockIdx.x * 128;

  #pragma unroll
  for (int r = 0; r < 8; ++r) {
    int idx = tid + 256 * r;
    int row = idx >> 4, seg = idx & 15;
    *(uint4*)&As[row * 136 + seg * 8] =
        *(const uint4*)&o_ws[(m0 + row) * 128 + seg * 8];
    *(uint4*)&Bs[row * 136 + seg * 8] =
        *(const uint4*)&woT[(size_t)row * 128 + seg * 8];
  }
  __syncthreads();

  f32x4 acc[2][8];
  #pragma unroll
  for (int mi = 0; mi < 2; ++mi)
    #pragma unroll
    for (int ni = 0; ni < 8; ++ni) {
      acc[mi][ni][0] = 0.f; acc[mi][ni][1] = 0.f;
      acc[mi][ni][2] = 0.f; acc[mi][ni][3] = 0.f;
    }
  #pragma unroll
  for (int kk = 0; kk < 4; ++kk) {
    bf16x8 a_[2];
    #pragma unroll
    for (int mi = 0; mi < 2; ++mi)
      a_[mi] = *(const bf16x8*)&As[(w * 32 + mi * 16 + q15) * 136 +
                                   kk * 32 + quad * 8];
    #pragma unroll
    for (int ni = 0; ni < 8; ++ni) {
      bf16x8 b_ = *(const bf16x8*)&Bs[(ni * 16 + q15) * 136 + kk * 32 + quad * 8];
      #pragma unroll
      for (int mi = 0; mi < 2; ++mi)
        acc[mi][ni] = __builtin_amdgcn_mfma_f32_16x16x32_bf16(
            a_[mi], b_, acc[mi][ni], 0, 0, 0);
    }
  }
  #pragma unroll
  for (int ni = 0; ni < 8; ++ni) {
    float bov = bo[ni * 16 + q15];
    #pragma unroll
    for (int mi = 0; mi < 2; ++mi)
      #pragma unroll
      for (int r = 0; r < 4; ++r) {
        int rowL = w * 32 + mi * 16 + quad * 4 + r;
        out[(m0 + rowL) * Cc + ni * 16 + q15] = acc[mi][ni][r] + bov;
      }
  }
}

// ---------------------------------------------------------------------------
extern "C" void kernel_launch(void* const* d_in, const int* in_sizes, int n_in,
                              void* d_out, int out_size, void* d_ws, size_t ws_size,
                              hipStream_t stream) {
  const float* x     = (const float*)d_in[0];
  const float* mask  = (const float*)d_in[1];
  const float* gamma = (const float*)d_in[2];
  const float* beta  = (const float*)d_in[3];
  const float* wb    = (const float*)d_in[4];
  const float* wq    = (const float*)d_in[5];
  const float* wk    = (const float*)d_in[6];
  const float* wv    = (const float*)d_in[7];
  const float* wg    = (const float*)d_in[8];
  const float* bg    = (const float*)d_in[9];
  const float* wo    = (const float*)d_in[10];
  const float* bo    = (const float*)d_in[11];
  float* out = (float*)d_out;

  char* ws = (char*)d_ws;
  ushort_t* xnb   = (ushort_t*)ws;                         // also o_ws (reused)
  ushort_t* qkvg  = (ushort_t*)(ws + (size_t)NPOS * 128 * 2);
  float*    bias3 = (float*)(ws + (size_t)NPOS * 128 * 2
                                + (size_t)4 * NHh * NPOS * 32 * 2);
  ushort_t* wBt   = (ushort_t*)((char*)bias3 + (size_t)NHh * NPOS * 4);
  ushort_t* woT   = wBt + 65536;
  float*    mb_ws = (float*)(woT + 16384);
  ushort_t* o_ws  = xnb;   // xnb is dead after k_proj

  hipLaunchKernelGGL(k_wt, dim3(80), dim3(256), 0, stream,
                     wq, wk, wv, wg, wo, wBt, woT);
  hipLaunchKernelGGL(k_ln, dim3(NPOS / 4), dim3(256), 0, stream,
                     x, gamma, beta, wb, mask, (unsigned int*)xnb, bias3, mb_ws);
  hipLaunchKernelGGL(k_proj, dim3(NPOS / 128), dim3(256), 0, stream,
                     xnb, wBt, bg, qkvg);
  hipLaunchKernelGGL(k_attn, dim3(12, Nn), dim3(256), 0, stream,
                     qkvg, bias3, mb_ws, o_ws);
  hipLaunchKernelGGL(k_out, dim3(NPOS / 128), dim3(256), 0, stream,
                     o_ws, woT, bo, out);
}

// Round 5
// 352.459 us; speedup vs baseline: 1.2635x; 1.0571x over previous
//
#include <hip/hip_runtime.h>

#define Nn 384
#define Cc 128
#define DHh 32
#define NHh 4
#define NPOS (Nn*Nn)
#define LOG2E 1.4426950408889634f

typedef unsigned short ushort_t;
typedef __attribute__((ext_vector_type(8))) short bf16x8;
typedef __attribute__((ext_vector_type(4))) float f32x4;
typedef __attribute__((ext_vector_type(16))) float f32x16;
typedef __attribute__((ext_vector_type(2))) int i32x2;
typedef __attribute__((ext_vector_type(4))) int i32x4;

__device__ __forceinline__ ushort_t f2bf(float f) {
  union { float f; unsigned int u; } v; v.f = f;
  unsigned int r = v.u + 0x7fffu + ((v.u >> 16) & 1u);   // RNE
  return (ushort_t)(r >> 16);
}
__device__ __forceinline__ float bf2f(ushort_t u) {
  union { unsigned int u; float f; } v; v.u = ((unsigned int)u) << 16;
  return v.f;
}
__device__ __forceinline__ int cvt_pk_bf16(float a, float b) {
  int r;
  asm("v_cvt_pk_bf16_f32 %0, %1, %2" : "=v"(r) : "v"(a), "v"(b));
  return r;   // lo16 = bf16(a), hi16 = bf16(b)
}

// ---------------------------------------------------------------------------
// Kernel 0: wBt[512][128] bf16 = concat(wq,wk,wv,wg); q rows scaled by
// (1/sqrt(32))*log2e (exp2 softmax trick). woT[128][128] bf16 = wo cast.
// ---------------------------------------------------------------------------
__global__ __launch_bounds__(256) void k_wt(const float* __restrict__ wq,
    const float* __restrict__ wk, const float* __restrict__ wv,
    const float* __restrict__ wg, const float* __restrict__ wo,
    ushort_t* __restrict__ wBt, ushort_t* __restrict__ woT) {
  for (int rep = 0; rep < 4; ++rep) {
    int idx = blockIdx.x * 256 + threadIdx.x + rep * 20480;  // 80 blocks
    if (idx < 65536) {
      int c = idx >> 7, k = idx & 127;
      int mat = c >> 7, row = c & 127;
      const float* src;
      float scale = 1.0f;
      if (mat == 0)      { src = wq; scale = 0.17677669529663687f * LOG2E; }
      else if (mat == 1) { src = wk; }
      else if (mat == 2) { src = wv; }
      else               { src = wg; }
      wBt[idx] = f2bf(src[row * 128 + k] * scale);
    } else {
      int j = idx - 65536;
      woT[j] = f2bf(wo[j]);
    }
  }
}

// ---------------------------------------------------------------------------
// Kernel 1: LayerNorm, HALF-WAVE (32 lanes) per position, 4 ch/lane via
// float4.  Outputs: xn bf16 (uint2 stores); bias3[h][k>>2][q][k&3] fp32
// pre-scaled by log2e; mbias[i][k] = (mask-1)*1e9*log2e.
// ---------------------------------------------------------------------------
__global__ __launch_bounds__(256) void k_ln(const float* __restrict__ x,
    const float* __restrict__ gamma, const float* __restrict__ beta,
    const float* __restrict__ wb, const float* __restrict__ mask,
    unsigned int* __restrict__ xnb, float* __restrict__ bias3,
    float* __restrict__ mb_ws) {
  int grp = threadIdx.x >> 5, g = threadIdx.x & 31;
  int p = blockIdx.x * 8 + grp;
  int i = p / Nn, j = p - i * Nn;
  f32x4 xv = *(const f32x4*)&x[(size_t)p * Cc + g * 4];
  float s = xv[0] + xv[1] + xv[2] + xv[3];
  #pragma unroll
  for (int off = 1; off < 32; off <<= 1) s += __shfl_xor(s, off, 64);
  float mu = s * (1.0f / Cc);
  float d0 = xv[0] - mu, d1 = xv[1] - mu, d2 = xv[2] - mu, d3 = xv[3] - mu;
  float sq = d0 * d0 + d1 * d1 + d2 * d2 + d3 * d3;
  #pragma unroll
  for (int off = 1; off < 32; off <<= 1) sq += __shfl_xor(sq, off, 64);
  float rs = rsqrtf(sq * (1.0f / Cc) + 1e-5f);
  f32x4 g4 = *(const f32x4*)&gamma[g * 4];
  f32x4 b4 = *(const f32x4*)&beta[g * 4];
  float xn0 = d0 * rs * g4[0] + b4[0];
  float xn1 = d1 * rs * g4[1] + b4[1];
  float xn2 = d2 * rs * g4[2] + b4[2];
  float xn3 = d3 * rs * g4[3] + b4[3];
  uint2 pk;
  pk.x = (unsigned int)f2bf(xn0) | ((unsigned int)f2bf(xn1) << 16);
  pk.y = (unsigned int)f2bf(xn2) | ((unsigned int)f2bf(xn3) << 16);
  *(uint2*)&xnb[(size_t)p * 64 + g * 2] = pk;
  #pragma unroll
  for (int h = 0; h < NHh; ++h) {
    f32x4 w4 = *(const f32x4*)&wb[h * Cc + g * 4];
    float t = xn0 * w4[0] + xn1 * w4[1] + xn2 * w4[2] + xn3 * w4[3];
    #pragma unroll
    for (int off = 1; off < 32; off <<= 1) t += __shfl_xor(t, off, 64);
    // bias3[h][j>>2][i][j&3]  (q = i is the row dim of scores, k = j)
    if (g == 0)
      bias3[(size_t)h * NPOS + (size_t)(j >> 2) * (Nn * 4) + i * 4 + (j & 3)] =
          t * LOG2E;
  }
  if (g == 1) mb_ws[p] = (mask[p] - 1.0f) * (1e9f * LOG2E);
}

// ---------------------------------------------------------------------------
// Kernel 2: projection GEMM via MFMA (round-2 version, known good), looping
// all 8 n-chunks per block so the A-tile is staged and frag-loaded ONCE.
// Cs aliases Bs. LDS 53248 -> 3 blk/CU.
// ---------------------------------------------------------------------------
__global__ __launch_bounds__(256, 3) void k_proj(const ushort_t* __restrict__ xnb,
    const ushort_t* __restrict__ wBt, const float* __restrict__ bg,
    ushort_t* __restrict__ qkvg) {
  __shared__ __align__(16) char plds[34816 + 18432];
  ushort_t* As = (ushort_t*)plds;              // [128][136]
  ushort_t* Bs = (ushort_t*)(plds + 34816);    // [64][136]  (17408 B)
  ushort_t* Cs = (ushort_t*)(plds + 34816);    // [128][72]  (18432 B, alias)
  const int tid = threadIdx.x, lane = tid & 63, w = tid >> 6;
  const int q15 = lane & 15, quad = lane >> 4;
  const int m0 = blockIdx.x * 128;

  #pragma unroll
  for (int r = 0; r < 8; ++r) {
    int idx = tid + 256 * r;
    int row = idx >> 4, seg = idx & 15;
    *(uint4*)&As[row * 136 + seg * 8] =
        *(const uint4*)&xnb[(size_t)(m0 + row) * 128 + seg * 8];
  }
  __syncthreads();
  bf16x8 af[4][2];
  #pragma unroll
  for (int kk = 0; kk < 4; ++kk)
    #pragma unroll
    for (int mi = 0; mi < 2; ++mi)
      af[kk][mi] = *(const bf16x8*)&As[(w * 32 + mi * 16 + q15) * 136 +
                                       kk * 32 + quad * 8];

  for (int nb = 0; nb < 8; ++nb) {
    #pragma unroll
    for (int r = 0; r < 4; ++r) {
      int idx = tid + 256 * r;
      int row = idx >> 4, seg = idx & 15;
      *(uint4*)&Bs[row * 136 + seg * 8] =
          *(const uint4*)&wBt[(size_t)(nb * 64 + row) * 128 + seg * 8];
    }
    __syncthreads();

    f32x4 acc[2][4];
    #pragma unroll
    for (int mi = 0; mi < 2; ++mi)
      #pragma unroll
      for (int ni = 0; ni < 4; ++ni) {
        float init = 0.0f;
        if (nb >= 6) init = bg[(nb & 1) * 64 + ni * 16 + q15];
        acc[mi][ni][0] = init; acc[mi][ni][1] = init;
        acc[mi][ni][2] = init; acc[mi][ni][3] = init;
      }
    #pragma unroll
    for (int kk = 0; kk < 4; ++kk) {
      bf16x8 bf[4];
      #pragma unroll
      for (int ni = 0; ni < 4; ++ni)
        bf[ni] = *(const bf16x8*)&Bs[(ni * 16 + q15) * 136 + kk * 32 + quad * 8];
      #pragma unroll
      for (int mi = 0; mi < 2; ++mi)
        #pragma unroll
        for (int ni = 0; ni < 4; ++ni)
          acc[mi][ni] = __builtin_amdgcn_mfma_f32_16x16x32_bf16(
              af[kk][mi], bf[ni], acc[mi][ni], 0, 0, 0);
    }
    __syncthreads();                 // Bs frag reads done (Cs aliases Bs)
    #pragma unroll
    for (int mi = 0; mi < 2; ++mi)
      #pragma unroll
      for (int ni = 0; ni < 4; ++ni)
        #pragma unroll
        for (int r = 0; r < 4; ++r) {
          int rowL = w * 32 + mi * 16 + quad * 4 + r;
          Cs[rowL * 72 + ni * 16 + q15] = f2bf(acc[mi][ni][r]);
        }
    __syncthreads();
    const int mat = nb >> 1;
    #pragma unroll
    for (int r = 0; r < 4; ++r) {
      int idx = tid + 256 * r;
      int row = idx >> 3, seg = idx & 7;
      int cl = (nb & 1) * 64 + seg * 8;
      int hh = cl >> 5, dd = cl & 31;
      uint4 v = *(const uint4*)&Cs[row * 72 + seg * 8];
      *(uint4*)&qkvg[(size_t)mat * (NHh * (size_t)NPOS * 32) +
                     (size_t)hh * ((size_t)NPOS * 32) +
                     (size_t)(m0 + row) * 32 + dd] = v;
    }
    __syncthreads();                 // Cs reads done before next Bs stage
  }
}

// ---------------------------------------------------------------------------
// Kernel 3: swapped-operand 32x32 MFMA flash attention (round-2 version),
// softmax fully in registers; P via cvt_pk + permlane32_swap; blocked bias3
// C-init (float4); K/V^T double-buffered XOR-swizzled LDS; 1 barrier/chunk.
// ---------------------------------------------------------------------------
__global__ __launch_bounds__(256, 4) void k_attn(const ushort_t* __restrict__ qkvg,
    const float* __restrict__ bias3, const float* __restrict__ mb_ws,
    ushort_t* __restrict__ o_ws) {
  __shared__ __align__(16) char lds[33280];
  ushort_t* KsB = (ushort_t*)lds;              // 2 x [128][32] (8192 B each)
  ushort_t* VtB = (ushort_t*)(lds + 16384);    // 2 x [32][128] (8192 B each)
  float*  lsmem = (float*)(lds + 32768);       // [128] row sums (per-wave 32)

  const int tid = threadIdx.x, lane = tid & 63, w = tid >> 6;
  const int ql = lane & 31, h5 = lane >> 5;
  const int h  = blockIdx.x / 3;
  const int qt = blockIdx.x % 3;
  const int i  = blockIdx.y;
  const int q0 = qt * 128;

  const ushort_t* q_all = qkvg;
  const ushort_t* k_all = qkvg + (size_t)1 * NHh * NPOS * 32;
  const ushort_t* v_all = qkvg + (size_t)2 * NHh * NPOS * 32;
  const ushort_t* g_all = qkvg + (size_t)3 * NHh * NPOS * 32;
  const size_t hbase = ((size_t)h * NPOS + (size_t)i * Nn) * 32;
  const float* brow = bias3 + (size_t)h * NPOS;   // [k>>2][q][k&3], *log2e
  const float* mrow = mb_ws + (size_t)i * Nn;     // (mask-1)*1e9*log2e

  const int qglob = q0 + w * 32 + ql;
  // Q fragments direct from global (once per block; L2-resident)
  const ushort_t* qp = q_all + hbase + (size_t)qglob * 32;
  const bf16x8 qf0 = *(const bf16x8*)&qp[h5 * 8];        // ch  0..15 half
  const bf16x8 qf1 = *(const bf16x8*)&qp[16 + h5 * 8];   // ch 16..31 half

  f32x16 oacc;
  #pragma unroll
  for (int r = 0; r < 16; ++r) oacc[r] = 0.f;
  float lsum = 0.f;

  const int swk = (ql >> 1) & 3;   // K-tile seg swizzle (read side)
  const int swv = (ql >> 1) & 7;   // V^T k-block swizzle (read side)

  for (int ch = 0; ch < 3; ++ch) {
    const int kbase = ch * 128;
    ushort_t* Ksb = KsB + (ch & 1) * 4096;
    ushort_t* Vtb = VtB + (ch & 1) * 4096;
    // ---- stage K chunk [128][32], seg ^= (row>>1)&3  (bank-conflict-free)
    #pragma unroll
    for (int r = 0; r < 2; ++r) {
      int idx = tid + 256 * r;
      int row = idx >> 2, seg = idx & 3;
      *(uint4*)&Ksb[row * 32 + (seg ^ ((row >> 1) & 3)) * 8] =
          *(const uint4*)&k_all[hbase + (size_t)(kbase + row) * 32 + seg * 8];
    }
    // ---- stage V^T [32 d][128 k] via dword-wide 2x2 transpose,
    //      k-block ^= (d>>1)&7  (2-way max on store & read)
    #pragma unroll
    for (int r = 0; r < 4; ++r) {
      int idx = tid + 256 * r;
      int dp = idx & 15, kp = idx >> 4;
      unsigned int a0 = *(const unsigned int*)
          &v_all[hbase + (size_t)(kbase + 2 * kp) * 32 + dp * 2];
      unsigned int a1 = *(const unsigned int*)
          &v_all[hbase + (size_t)(kbase + 2 * kp + 1) * 32 + dp * 2];
      unsigned int lo = (a0 & 0xffffu) | (a1 << 16);   // d=2dp   : k, k+1
      unsigned int hi = (a0 >> 16) | (a1 & 0xffff0000u); // d=2dp+1
      unsigned int* v32 = (unsigned int*)Vtb;
      int col = ((kp >> 2) ^ (dp & 7)) * 4 + (kp & 3);
      v32[(2 * dp) * 64 + col] = lo;
      v32[(2 * dp + 1) * 64 + col] = hi;
    }
    __syncthreads();   // only barrier in the chunk (dbuf covers the rest)

    #pragma unroll
    for (int t = 0; t < 4; ++t) {
      // K fragments: rows = k (lane&31), elems = channel half
      bf16x8 kf0 = *(const bf16x8*)&Ksb[(t * 32 + ql) * 32 + ((h5)     ^ swk) * 8];
      bf16x8 kf1 = *(const bf16x8*)&Ksb[(t * 32 + ql) * 32 + ((2 + h5) ^ swk) * 8];
      // C-init = tri_bias (float4 over 4 consecutive k) + mask bias (float4)
      const int K0 = kbase + t * 32 + 4 * h5;
      f32x16 acc;
      #pragma unroll
      for (int g = 0; g < 4; ++g) {
        f32x4 b4 = *(const f32x4*)
            &brow[(size_t)((K0 >> 2) + 2 * g) * (Nn * 4) + qglob * 4];
        f32x4 m4 = *(const f32x4*)&mrow[K0 + 8 * g];
        acc[4 * g + 0] = b4[0] + m4[0];
        acc[4 * g + 1] = b4[1] + m4[1];
        acc[4 * g + 2] = b4[2] + m4[2];
        acc[4 * g + 3] = b4[3] + m4[3];
      }
      // S^T = K Q^T + C   (rows = k in reg pattern, cols = q = lane&31)
      acc = __builtin_amdgcn_mfma_f32_32x32x16_bf16(kf0, qf0, acc, 0, 0, 0);
      acc = __builtin_amdgcn_mfma_f32_32x32x16_bf16(kf1, qf1, acc, 0, 0, 0);
      // softmax in registers: exp2 (inputs pre-scaled), in-lane row sums,
      // packed bf16:  pk[r>>1] = {P[k], P[k+1]}
      int pk[8];
      #pragma unroll
      for (int r = 0; r < 16; r += 2) {
        float e0 = exp2f(acc[r]);
        float e1 = exp2f(acc[r + 1]);
        lsum += e0 + e1;
        pk[r >> 1] = cvt_pk_bf16(e0, e1);
      }
      // PV for k-slices kt = 2t, 2t+1: assemble pa via permlane32_swap.
      //  swap(pk[4b],pk[4b+2]) -> (pa.d0, pa.d2); (+1,+3) -> (d1, d3)
      #pragma unroll
      for (int b2 = 0; b2 < 2; ++b2) {
        i32x2 s0 = __builtin_amdgcn_permlane32_swap(pk[4 * b2 + 0],
                                                    pk[4 * b2 + 2], false, false);
        i32x2 s1 = __builtin_amdgcn_permlane32_swap(pk[4 * b2 + 1],
                                                    pk[4 * b2 + 3], false, false);
        union { i32x4 i; bf16x8 b; } pu;
        pu.i[0] = s0[0]; pu.i[1] = s1[0]; pu.i[2] = s0[1]; pu.i[3] = s1[1];
        int kt = 2 * t + b2;
        bf16x8 vb = *(const bf16x8*)
            &Vtb[ql * 128 + ((2 * kt + h5) ^ swv) * 8];
        oacc = __builtin_amdgcn_mfma_f32_32x32x16_bf16(pu.b, vb, oacc, 0, 0, 0);
      }
    }
  }

  // epilogue: complete row sums (partner half holds complementary k set),
  // broadcast per-wave via LDS, normalize, gate, store o_gated bf16.
  float lsf = lsum + __shfl_xor(lsum, 32, 64);
  if (lane < 32) lsmem[w * 32 + ql] = lsf;
  float inv[16];
  #pragma unroll
  for (int g = 0; g < 4; ++g) {
    f32x4 lv = *(const f32x4*)&lsmem[w * 32 + g * 8 + 4 * h5];
    #pragma unroll
    for (int j = 0; j < 4; ++j) inv[g * 4 + j] = 1.0f / lv[j];
  }
  #pragma unroll
  for (int r = 0; r < 16; ++r) {
    int qloc = w * 32 + (r & 3) + 8 * (r >> 2) + 4 * h5;
    int posg = i * Nn + q0 + qloc;
    float gpre = bf2f(g_all[((size_t)h * NPOS + posg) * 32 + ql]);
    float gate = 1.0f / (1.0f + __expf(-gpre));
    o_ws[(size_t)posg * Cc + h * DHh + ql] = f2bf(oacc[r] * inv[r] * gate);
  }
}

// ---------------------------------------------------------------------------
// Kernel 4: out = o_gated @ wo^T + bo.  Only the A-tile is LDS-staged; woT
// (32 KB, shared by all blocks, L1/L2-resident) is read directly from global.
// LDS 34816 -> 4 blk/CU; ni-outer loop keeps acc at 8 live regs.
// ---------------------------------------------------------------------------
__global__ __launch_bounds__(256, 4) void k_out(const ushort_t* __restrict__ o_ws,
    const ushort_t* __restrict__ woT, const float* __restrict__ bo,
    float* __restrict__ out) {
  __shared__ ushort_t As[128 * 136];
  const int tid = threadIdx.x, lane = tid & 63, w = tid >> 6;
  const int q15 = lane & 15, quad = lane >> 4;
  const size_t m0 = (size_t)blockIdx.x * 128;

  #pragma unroll
  for (int r = 0; r < 8; ++r) {
    int idx = tid + 256 * r;
    int row = idx >> 4, seg = idx & 15;
    *(uint4*)&As[row * 136 + seg * 8] =
        *(const uint4*)&o_ws[(m0 + row) * 128 + seg * 8];
  }
  __syncthreads();

  bf16x8 af[4][2];
  #pragma unroll
  for (int kk = 0; kk < 4; ++kk)
    #pragma unroll
    for (int mi = 0; mi < 2; ++mi)
      af[kk][mi] = *(const bf16x8*)&As[(w * 32 + mi * 16 + q15) * 136 +
                                       kk * 32 + quad * 8];

  #pragma unroll
  for (int ni = 0; ni < 8; ++ni) {
    f32x4 acc[2];
    #pragma unroll
    for (int mi = 0; mi < 2; ++mi) {
      acc[mi][0] = 0.f; acc[mi][1] = 0.f; acc[mi][2] = 0.f; acc[mi][3] = 0.f;
    }
    #pragma unroll
    for (int kk = 0; kk < 4; ++kk) {
      bf16x8 b_ = *(const bf16x8*)&woT[(size_t)(ni * 16 + q15) * 128 +
                                       kk * 32 + quad * 8];
      #pragma unroll
      for (int mi = 0; mi < 2; ++mi)
        acc[mi] = __builtin_amdgcn_mfma_f32_16x16x32_bf16(
            af[kk][mi], b_, acc[mi], 0, 0, 0);
    }
    float bov = bo[ni * 16 + q15];
    #pragma unroll
    for (int mi = 0; mi < 2; ++mi)
      #pragma unroll
      for (int r = 0; r < 4; ++r) {
        int rowL = w * 32 + mi * 16 + quad * 4 + r;
        out[(m0 + rowL) * Cc + ni * 16 + q15] = acc[mi][r] + bov;
      }
  }
}

// ---------------------------------------------------------------------------
extern "C" void kernel_launch(void* const* d_in, const int* in_sizes, int n_in,
                              void* d_out, int out_size, void* d_ws, size_t ws_size,
                              hipStream_t stream) {
  const float* x     = (const float*)d_in[0];
  const float* mask  = (const float*)d_in[1];
  const float* gamma = (const float*)d_in[2];
  const float* beta  = (const float*)d_in[3];
  const float* wb    = (const float*)d_in[4];
  const float* wq    = (const float*)d_in[5];
  const float* wk    = (const float*)d_in[6];
  const float* wv    = (const float*)d_in[7];
  const float* wg    = (const float*)d_in[8];
  const float* bg    = (const float*)d_in[9];
  const float* wo    = (const float*)d_in[10];
  const float* bo    = (const float*)d_in[11];
  float* out = (float*)d_out;

  char* ws = (char*)d_ws;
  ushort_t* xnb   = (ushort_t*)ws;                         // also o_ws (reused)
  ushort_t* qkvg  = (ushort_t*)(ws + (size_t)NPOS * 128 * 2);
  float*    bias3 = (float*)(ws + (size_t)NPOS * 128 * 2
                                + (size_t)4 * NHh * NPOS * 32 * 2);
  ushort_t* wBt   = (ushort_t*)((char*)bias3 + (size_t)NHh * NPOS * 4);
  ushort_t* woT   = wBt + 65536;
  float*    mb_ws = (float*)(woT + 16384);
  ushort_t* o_ws  = xnb;   // xnb is dead after k_proj

  hipLaunchKernelGGL(k_wt, dim3(80), dim3(256), 0, stream,
                     wq, wk, wv, wg, wo, wBt, woT);
  hipLaunchKernelGGL(k_ln, dim3(NPOS / 8), dim3(256), 0, stream,
                     x, gamma, beta, wb, mask, (unsigned int*)xnb, bias3, mb_ws);
  hipLaunchKernelGGL(k_proj, dim3(NPOS / 128), dim3(256), 0, stream,
                     xnb, wBt, bg, qkvg);
  hipLaunchKernelGGL(k_attn, dim3(12, Nn), dim3(256), 0, stream,
                     qkvg, bias3, mb_ws, o_ws);
  hipLaunchKernelGGL(k_out, dim3(NPOS / 128), dim3(256), 0, stream,
                     o_ws, woT, bo, out);
}